// Round 4
// baseline (727.739 us; speedup 1.0000x reference)
//
#include <hip/hip_runtime.h>
#include <hip/hip_fp16.h>

#define BATCH 65536
#define DIM   256
#define CODES 1024
#define TAU   0.35f

typedef _Float16 f16x8 __attribute__((ext_vector_type(8)));
typedef float    f32x4 __attribute__((ext_vector_type(4)));

// ---------------------------------------------------------------------------
// Prep: E -> fp16 + exact |e|^2 per code (f32)
// ---------------------------------------------------------------------------
__global__ void vq_prep(const float* __restrict__ E, float* __restrict__ enorm,
                        unsigned short* __restrict__ Eh) {
    int k = blockIdx.x;      // code
    int lane = threadIdx.x;  // 0..63
    const float4 v = *(const float4*)(E + (size_t)k * DIM + lane * 4);
    float s = v.x * v.x + v.y * v.y + v.z * v.z + v.w * v.w;
    ushort4 hv;
    hv.x = __half_as_ushort(__float2half(v.x));
    hv.y = __half_as_ushort(__float2half(v.y));
    hv.z = __half_as_ushort(__float2half(v.z));
    hv.w = __half_as_ushort(__float2half(v.w));
    *(ushort4*)(Eh + (size_t)k * DIM + lane * 4) = hv;
    s += __shfl_down(s, 32);
    s += __shfl_down(s, 16);
    s += __shfl_down(s, 8);
    s += __shfl_down(s, 4);
    s += __shfl_down(s, 2);
    s += __shfl_down(s, 1);
    if (lane == 0) enorm[k] = s;
}

// ---------------------------------------------------------------------------
// Fused main, BARRIER-FREE: fp16 MFMA distances with B streamed from L2
// directly into VGPRs (Eh = 512 KB, L2-resident per XCD). No LDS, no GLL,
// no __syncthreads -> waves fully independent, occupancy = VGPR-bound only.
//   block = 256 thr (4 waves), 32 rows/wave -> 128 rows/block, grid = 512.
//   Per tile (16 codes): 8 x global_load_dwordx4 (L2) + 16 MFMA (2 chains).
//   Near-ties (margin < TAU) listed; vq_repair recomputes exactly in fp32
//   and rewrites those rows' outputs.
// ---------------------------------------------------------------------------
__global__ __launch_bounds__(256, 3) void vq_main(
    const float* __restrict__ X,
    const unsigned short* __restrict__ Eh,
    const float* __restrict__ enorm,
    const float* __restrict__ E,
    float* __restrict__ loss, float* __restrict__ qst, float* __restrict__ onehot,
    int* __restrict__ cnt, int* __restrict__ list) {

    const int lane = threadIdx.x & 63;
    const int w    = threadIdx.x >> 6;       // wave 0..3
    const int m    = lane & 15;              // A row-in-16 / B,C code col
    const int quad = lane >> 4;              // 0..3
    const int row0 = blockIdx.x * 128 + w * 32;

    // ---- A fragments: 2 row-groups x 8 ksteps fp16 (64 VGPRs) ----
    f16x8 a0[8], a1[8];
    #pragma unroll
    for (int s = 0; s < 8; ++s) {
        const float* xr0 = X + (size_t)(row0 + m) * DIM + quad * 8 + s * 32;
        const float* xr1 = X + (size_t)(row0 + 16 + m) * DIM + quad * 8 + s * 32;
        float4 p0 = *(const float4*)(xr0);
        float4 p1 = *(const float4*)(xr0 + 4);
        float4 q0 = *(const float4*)(xr1);
        float4 q1 = *(const float4*)(xr1 + 4);
        a0[s][0] = (_Float16)p0.x; a0[s][1] = (_Float16)p0.y;
        a0[s][2] = (_Float16)p0.z; a0[s][3] = (_Float16)p0.w;
        a0[s][4] = (_Float16)p1.x; a0[s][5] = (_Float16)p1.y;
        a0[s][6] = (_Float16)p1.z; a0[s][7] = (_Float16)p1.w;
        a1[s][0] = (_Float16)q0.x; a1[s][1] = (_Float16)q0.y;
        a1[s][2] = (_Float16)q0.z; a1[s][3] = (_Float16)q0.w;
        a1[s][4] = (_Float16)q1.x; a1[s][5] = (_Float16)q1.y;
        a1[s][6] = (_Float16)q1.z; a1[s][7] = (_Float16)q1.w;
    }

    float best[2][4], sec[2][4];
    int   bidx[2][4];
    #pragma unroll
    for (int g = 0; g < 2; ++g)
        #pragma unroll
        for (int r = 0; r < 4; ++r) {
            best[g][r] = 3.4e38f; sec[g][r] = 3.4e38f; bidx[g][r] = 0;
        }

    for (int t = 0; t < 64; ++t) {
        // B frags straight from L2: lane (m,quad) reads Eh[code t*16+m][quad*8 + s*32 ..]
        const unsigned short* bp = Eh + (size_t)(t * 16 + m) * DIM + quad * 8;
        f16x8 b[8];
        #pragma unroll
        for (int s = 0; s < 8; ++s) b[s] = *(const f16x8*)(bp + s * 32);
        f32x4 acc0 = {0.f, 0.f, 0.f, 0.f}, acc1 = {0.f, 0.f, 0.f, 0.f};
        #pragma unroll
        for (int s = 0; s < 8; ++s) {
            acc0 = __builtin_amdgcn_mfma_f32_16x16x32_f16(a0[s], b[s], acc0, 0, 0, 0);
            acc1 = __builtin_amdgcn_mfma_f32_16x16x32_f16(a1[s], b[s], acc1, 0, 0, 0);
        }
        // C layout: col = lane&15 (code), row = quad*4 + reg
        const float es = enorm[t * 16 + m];   // 4 KB, L1-hot
        const int   c  = t * 16 + m;
        #pragma unroll
        for (int r = 0; r < 4; ++r) {
            float d0 = __builtin_fmaf(-2.0f, acc0[r], es);
            if (d0 < best[0][r]) { sec[0][r] = best[0][r]; best[0][r] = d0; bidx[0][r] = c; }
            else if (d0 < sec[0][r]) sec[0][r] = d0;
            float d1 = __builtin_fmaf(-2.0f, acc1[r], es);
            if (d1 < best[1][r]) { sec[1][r] = best[1][r]; best[1][r] = d1; bidx[1][r] = c; }
            else if (d1 < sec[1][r]) sec[1][r] = d1;
        }
    }

    // cross-lane argmin reduce over the 16 code-columns (low 4 lane bits)
    #pragma unroll
    for (int g = 0; g < 2; ++g) {
        #pragma unroll
        for (int r = 0; r < 4; ++r) {
            float b0 = best[g][r], s0 = sec[g][r];
            int   i0 = bidx[g][r];
            #pragma unroll
            for (int msk = 1; msk < 16; msk <<= 1) {
                float ob = __shfl_xor(b0, msk);
                float os = __shfl_xor(s0, msk);
                int   oi = __shfl_xor(i0, msk);
                if (ob < b0 || (ob == b0 && oi < i0)) {
                    s0 = fminf(b0, os);
                    b0 = ob; i0 = oi;
                } else {
                    s0 = fminf(s0, ob);
                }
            }
            best[g][r] = b0; sec[g][r] = s0; bidx[g][r] = i0;
        }
    }

    // flag near-ties for exact repair (repair also rewrites their outputs)
    if (m == 0) {
        #pragma unroll
        for (int g = 0; g < 2; ++g)
            #pragma unroll
            for (int r = 0; r < 4; ++r)
                if (sec[g][r] - best[g][r] < TAU) {
                    int p = atomicAdd(cnt, 1);
                    if (p < BATCH) list[p] = row0 + g * 16 + quad * 4 + r;
                }
    }

    // ---- fused epilogue: this wave writes its 32 rows ----
    // row j: group j>>4, quad (j>>2)&3, reg j&3; reduced bidx is uniform
    // within each quad -> broadcast from lane q*16.
    #pragma unroll
    for (int j = 0; j < 32; ++j) {
        const int g = j >> 4, q = (j >> 2) & 3, r = j & 3;
        const int idx = __shfl(bidx[g][r], q << 4);
        const int row = row0 + j;
        const size_t xb = (size_t)row * DIM + lane * 4;
        float4 x = *(const float4*)(X + xb);
        float4 qv = *(const float4*)(E + (size_t)idx * DIM + lane * 4);
        float4 dl = {qv.x - x.x, qv.y - x.y, qv.z - x.z, qv.w - x.w};
        float4 lo = {0.25f * dl.x * dl.x, 0.25f * dl.y * dl.y,
                     0.25f * dl.z * dl.z, 0.25f * dl.w * dl.w};
        float4 qs = {x.x + dl.x, x.y + dl.y, x.z + dl.z, x.w + dl.w};
        *(float4*)(loss + xb) = lo;
        *(float4*)(qst + xb)  = qs;
        const size_t ob = (size_t)row * CODES;
        const int slot = idx >> 2, r3 = idx & 3;
        #pragma unroll
        for (int jj = 0; jj < 4; ++jj) {
            f32x4 z = {0.f, 0.f, 0.f, 0.f};
            if (slot == jj * 64 + lane) z[r3] = 1.0f;
            __builtin_nontemporal_store(z, (f32x4*)(onehot + ob + jj * 256 + lane * 4));
        }
    }
}

// ---------------------------------------------------------------------------
// Repair: exact fp32 argmin for flagged rows + REWRITE their output rows.
//   block = 256 thr (4 waves); wave w sweeps codes [256w, 256w+256);
//   grid-stride over the flag list. (Math unchanged — absmax==0 depends on it.)
// ---------------------------------------------------------------------------
__global__ __launch_bounds__(256) void vq_repair(
    const float* __restrict__ X, const float* __restrict__ E,
    const float* __restrict__ enorm,
    const int* __restrict__ cnt, const int* __restrict__ list,
    float* __restrict__ loss, float* __restrict__ qst, float* __restrict__ onehot) {
    __shared__ float wb[4];
    __shared__ int   wi[4];
    __shared__ int   sidx;
    int n = *cnt; if (n > BATCH) n = BATCH;
    const int lane = threadIdx.x & 63;
    const int w    = threadIdx.x >> 6;
    for (int i = blockIdx.x; i < n; i += gridDim.x) {
        const int row = list[i];
        const float4 xv = *(const float4*)(X + (size_t)row * DIM + lane * 4);
        float bb = 3.4e38f; int bi = 0;
        for (int j = 0; j < 256; j += 4) {
            const int c = w * 256 + j;
            const float* e0 = E + (size_t)c * DIM + lane * 4;
            float4 v0 = *(const float4*)(e0);
            float4 v1 = *(const float4*)(e0 + DIM);
            float4 v2 = *(const float4*)(e0 + 2 * DIM);
            float4 v3 = *(const float4*)(e0 + 3 * DIM);
            float s0 = xv.x * v0.x + xv.y * v0.y + xv.z * v0.z + xv.w * v0.w;
            float s1 = xv.x * v1.x + xv.y * v1.y + xv.z * v1.z + xv.w * v1.w;
            float s2 = xv.x * v2.x + xv.y * v2.y + xv.z * v2.z + xv.w * v2.w;
            float s3 = xv.x * v3.x + xv.y * v3.y + xv.z * v3.z + xv.w * v3.w;
            #pragma unroll
            for (int msk = 32; msk >= 1; msk >>= 1) {
                s0 += __shfl_xor(s0, msk);
                s1 += __shfl_xor(s1, msk);
                s2 += __shfl_xor(s2, msk);
                s3 += __shfl_xor(s3, msk);
            }
            float d0 = enorm[c]     - 2.0f * s0;
            float d1 = enorm[c + 1] - 2.0f * s1;
            float d2 = enorm[c + 2] - 2.0f * s2;
            float d3 = enorm[c + 3] - 2.0f * s3;
            // c ascending within wave -> strict < keeps lowest index
            if (d0 < bb) { bb = d0; bi = c; }
            if (d1 < bb) { bb = d1; bi = c + 1; }
            if (d2 < bb) { bb = d2; bi = c + 2; }
            if (d3 < bb) { bb = d3; bi = c + 3; }
        }
        if (lane == 0) { wb[w] = bb; wi[w] = bi; }
        __syncthreads();
        if (threadIdx.x == 0) {
            float fb = wb[0]; int fi = wi[0];
            #pragma unroll
            for (int k = 1; k < 4; ++k)
                if (wb[k] < fb || (wb[k] == fb && wi[k] < fi)) { fb = wb[k]; fi = wi[k]; }
            sidx = fi;
        }
        __syncthreads();
        const int fi = sidx;
        // rewrite outputs for this row with the exact index
        if (w == 0) {
            const size_t xb = (size_t)row * DIM + lane * 4;
            float4 x = *(const float4*)(X + xb);
            float4 q = *(const float4*)(E + (size_t)fi * DIM + lane * 4);
            float4 dl = {q.x - x.x, q.y - x.y, q.z - x.z, q.w - x.w};
            float4 lo = {0.25f * dl.x * dl.x, 0.25f * dl.y * dl.y,
                         0.25f * dl.z * dl.z, 0.25f * dl.w * dl.w};
            float4 qs = {x.x + dl.x, x.y + dl.y, x.z + dl.z, x.w + dl.w};
            *(float4*)(loss + xb) = lo;
            *(float4*)(qst + xb)  = qs;
        }
        {   // onehot row: 256 threads x f32x4 = 1024 floats
            const int t = threadIdx.x;
            f32x4 z = {0.f, 0.f, 0.f, 0.f};
            if ((fi >> 2) == t) z[fi & 3] = 1.0f;
            *(f32x4*)(onehot + (size_t)row * CODES + t * 4) = z;
        }
        __syncthreads();
    }
}

extern "C" void kernel_launch(void* const* d_in, const int* in_sizes, int n_in,
                              void* d_out, int out_size, void* d_ws, size_t ws_size,
                              hipStream_t stream) {
    const float* X = (const float*)d_in[0];   // (65536, 256)
    const float* E = (const float*)d_in[1];   // (1024, 256)
    float* out = (float*)d_out;
    float* loss   = out;
    float* qst    = out + (size_t)BATCH * DIM;
    float* onehot = out + (size_t)2 * BATCH * DIM;

    char* ws = (char*)d_ws;
    float*          enorm  = (float*)ws;                        // 4 KB
    unsigned short* Eh     = (unsigned short*)(ws + 4096);      // 512 KB
    int*            cnt    = (int*)(ws + 528384);               // 4 B
    int*            list   = (int*)(ws + 528448);               // 256 KB

    (void)hipMemsetAsync(cnt, 0, sizeof(int), stream);

    vq_prep<<<CODES, 64, 0, stream>>>(E, enorm, Eh);
    vq_main<<<BATCH / 128, 256, 0, stream>>>(X, Eh, enorm, E,
                                             loss, qst, onehot, cnt, list);
    vq_repair<<<2048, 256, 0, stream>>>(X, E, enorm, cnt, list,
                                        loss, qst, onehot);
}

// Round 5
// 622.914 us; speedup vs baseline: 1.1683x; 1.1683x over previous
//
#include <hip/hip_runtime.h>
#include <hip/hip_fp16.h>

#define BATCH 65536
#define DIM   256
#define CODES 1024
#define TAU   0.20f

typedef _Float16 f16x8 __attribute__((ext_vector_type(8)));
typedef float    f32x4 __attribute__((ext_vector_type(4)));

// async global->LDS, 16B per lane; LDS dest = uniform base + lane*16
#define GLL(gptr, lptr) \
    __builtin_amdgcn_global_load_lds( \
        (const __attribute__((address_space(1))) void*)(gptr), \
        (__attribute__((address_space(3))) void*)(lptr), 16, 0, 0)

// ---------------------------------------------------------------------------
// Prep: E -> fp16 + exact |e|^2 per code (f32)
// ---------------------------------------------------------------------------
__global__ void vq_prep(const float* __restrict__ E, float* __restrict__ enorm,
                        unsigned short* __restrict__ Eh) {
    int k = blockIdx.x;      // code
    int lane = threadIdx.x;  // 0..63
    const float4 v = *(const float4*)(E + (size_t)k * DIM + lane * 4);
    float s = v.x * v.x + v.y * v.y + v.z * v.z + v.w * v.w;
    ushort4 hv;
    hv.x = __half_as_ushort(__float2half(v.x));
    hv.y = __half_as_ushort(__float2half(v.y));
    hv.z = __half_as_ushort(__float2half(v.z));
    hv.w = __half_as_ushort(__float2half(v.w));
    *(ushort4*)(Eh + (size_t)k * DIM + lane * 4) = hv;
    s += __shfl_down(s, 32);
    s += __shfl_down(s, 16);
    s += __shfl_down(s, 8);
    s += __shfl_down(s, 4);
    s += __shfl_down(s, 2);
    s += __shfl_down(s, 1);
    if (lane == 0) enorm[k] = s;
}

// ---------------------------------------------------------------------------
// MEGAKERNEL: fp16 MFMA argmin + block-local exact repair + epilogue.
//   block = 512 thr (8 waves), 128 rows/block, grid = 512. One launch does
//   everything for its rows: no global flag list, no cnt memset, no separate
//   repair/epilogue dispatches. Near-ties (margin < TAU) are re-argmin'd in
//   exact fp32 by all 8 waves cooperatively (wave w sweeps codes
//   [128w,128w+128)), then the fused epilogue writes loss/qst/onehot from
//   the (possibly corrected) per-row index in LDS.
//   fp16 dot error sigma ~0.018 on d-differences; TAU=0.20 ~ 11 sigma.
// ---------------------------------------------------------------------------
__global__ __launch_bounds__(512, 4) void vq_fused(
    const float* __restrict__ X,
    const unsigned short* __restrict__ Eh,
    const float* __restrict__ enorm,
    const float* __restrict__ E,
    float* __restrict__ loss, float* __restrict__ qst, float* __restrict__ onehot) {

    // per buffer: 8 ksteps x 64 lanes x 8 fp16 = 4096 ushort = 8 KB
    __shared__ unsigned short Eb[2][4096];   // 16 KB
    __shared__ float EsL[CODES];             // 4 KB
    __shared__ int   ridx[128];              // per-row chosen index
    __shared__ int   flags[128];             // local rows needing exact repair
    __shared__ int   nflag;
    __shared__ float wrb[8];
    __shared__ int   wri[8];

    const int tid  = threadIdx.x;
    const int lane = tid & 63;
    const int w    = tid >> 6;               // wave 0..7 (stages k-slot w)
    const int m    = lane & 15;              // A row-in-16 / C code col
    const int quad = lane >> 4;              // 0..3
    const int row0 = blockIdx.x * 128;       // block base row
    const int wrow = row0 + w * 16;          // this wave's first row

    if (tid == 0) nflag = 0;

    // prologue: async-stage tile 0 into buf 0
    {
        const size_t rb0 = (size_t)m * DIM + w * 32 + quad * 8;
        GLL(Eh + rb0, &Eb[0][w * 512]);
    }

    for (int i = tid; i < CODES; i += 512) EsL[i] = enorm[i];

    // ---- A fragments: 16 rows, 8 ksteps fp16 (32 VGPRs) ----
    f16x8 ah[8];
    {
        const float* xr = X + (size_t)(wrow + m) * DIM + quad * 8;
        #pragma unroll
        for (int s = 0; s < 8; ++s) {
            float4 p0 = *(const float4*)(xr + s * 32);
            float4 p1 = *(const float4*)(xr + s * 32 + 4);
            ah[s][0] = (_Float16)p0.x; ah[s][1] = (_Float16)p0.y;
            ah[s][2] = (_Float16)p0.z; ah[s][3] = (_Float16)p0.w;
            ah[s][4] = (_Float16)p1.x; ah[s][5] = (_Float16)p1.y;
            ah[s][6] = (_Float16)p1.z; ah[s][7] = (_Float16)p1.w;
        }
    }

    __syncthreads();   // drains gll (vmcnt0) + EsL + nflag init

    float best[4], sec[4];
    int   bidx[4];
    #pragma unroll
    for (int i = 0; i < 4; ++i) { best[i] = 3.4e38f; sec[i] = 3.4e38f; bidx[i] = 0; }

    for (int t = 0; t < 64; ++t) {
        const int buf = t & 1;
        if (t < 63) {   // async prefetch next tile into other buffer
            const size_t rbn = (size_t)((t + 1) * 16 + m) * DIM + w * 32 + quad * 8;
            GLL(Eh + rbn, &Eb[buf ^ 1][w * 512]);
        }
        f32x4 accA = {0.f, 0.f, 0.f, 0.f}, accB = {0.f, 0.f, 0.f, 0.f};
        const unsigned short* b = &Eb[buf][0];
        #pragma unroll
        for (int s = 0; s < 4; ++s) {
            f16x8 bh = *(const f16x8*)(b + s * 512 + lane * 8);
            accA = __builtin_amdgcn_mfma_f32_16x16x32_f16(ah[s], bh, accA, 0, 0, 0);
        }
        #pragma unroll
        for (int s = 4; s < 8; ++s) {
            f16x8 bh = *(const f16x8*)(b + s * 512 + lane * 8);
            accB = __builtin_amdgcn_mfma_f32_16x16x32_f16(ah[s], bh, accB, 0, 0, 0);
        }
        // C layout: col = lane&15 (code), row = quad*4 + reg
        const float es = EsL[t * 16 + m];
        const int   c  = t * 16 + m;
        #pragma unroll
        for (int r = 0; r < 4; ++r) {
            float d = __builtin_fmaf(-2.0f, accA[r] + accB[r], es);
            if (d < best[r]) { sec[r] = best[r]; best[r] = d; bidx[r] = c; }
            else if (d < sec[r]) sec[r] = d;
        }
        __syncthreads();   // drains prefetch + protects buf^1 reuse
    }

    // cross-lane argmin reduce over the 16 code-columns (low 4 lane bits)
    #pragma unroll
    for (int i = 0; i < 4; ++i) {
        float b0 = best[i], s0 = sec[i];
        int   i0 = bidx[i];
        #pragma unroll
        for (int msk = 1; msk < 16; msk <<= 1) {
            float ob = __shfl_xor(b0, msk);
            float os = __shfl_xor(s0, msk);
            int   oi = __shfl_xor(i0, msk);
            if (ob < b0 || (ob == b0 && oi < i0)) {
                s0 = fminf(b0, os);
                b0 = ob; i0 = oi;
            } else {
                s0 = fminf(s0, ob);
            }
        }
        best[i] = b0; sec[i] = s0; bidx[i] = i0;
    }

    // publish per-row indices; flag near-ties into the block-local list
    if (m == 0) {
        #pragma unroll
        for (int r = 0; r < 4; ++r) {
            const int lrow = w * 16 + quad * 4 + r;
            ridx[lrow] = bidx[r];
            if (sec[r] - best[r] < TAU) {
                int p = atomicAdd(&nflag, 1);   // LDS atomic
                flags[p] = lrow;
            }
        }
    }
    __syncthreads();

    // ---- block-local exact repair: all 8 waves per flagged row ----
    const int nf = nflag;
    for (int f = 0; f < nf; ++f) {
        const int lrow = flags[f];
        const int row  = row0 + lrow;
        const float4 xv = *(const float4*)(X + (size_t)row * DIM + lane * 4);
        float bb = 3.4e38f; int bi = 0;
        for (int j = 0; j < 128; j += 4) {
            const int c = w * 128 + j;
            const float* e0 = E + (size_t)c * DIM + lane * 4;
            float4 v0 = *(const float4*)(e0);
            float4 v1 = *(const float4*)(e0 + DIM);
            float4 v2 = *(const float4*)(e0 + 2 * DIM);
            float4 v3 = *(const float4*)(e0 + 3 * DIM);
            float s0 = xv.x * v0.x + xv.y * v0.y + xv.z * v0.z + xv.w * v0.w;
            float s1 = xv.x * v1.x + xv.y * v1.y + xv.z * v1.z + xv.w * v1.w;
            float s2 = xv.x * v2.x + xv.y * v2.y + xv.z * v2.z + xv.w * v2.w;
            float s3 = xv.x * v3.x + xv.y * v3.y + xv.z * v3.z + xv.w * v3.w;
            #pragma unroll
            for (int msk = 32; msk >= 1; msk >>= 1) {
                s0 += __shfl_xor(s0, msk);
                s1 += __shfl_xor(s1, msk);
                s2 += __shfl_xor(s2, msk);
                s3 += __shfl_xor(s3, msk);
            }
            float d0 = enorm[c]     - 2.0f * s0;
            float d1 = enorm[c + 1] - 2.0f * s1;
            float d2 = enorm[c + 2] - 2.0f * s2;
            float d3 = enorm[c + 3] - 2.0f * s3;
            // c ascending within wave -> strict < keeps lowest index
            if (d0 < bb) { bb = d0; bi = c; }
            if (d1 < bb) { bb = d1; bi = c + 1; }
            if (d2 < bb) { bb = d2; bi = c + 2; }
            if (d3 < bb) { bb = d3; bi = c + 3; }
        }
        if (lane == 0) { wrb[w] = bb; wri[w] = bi; }
        __syncthreads();
        if (tid == 0) {
            float fb = wrb[0]; int fi = wri[0];
            #pragma unroll
            for (int k = 1; k < 8; ++k)
                if (wrb[k] < fb || (wrb[k] == fb && wri[k] < fi)) { fb = wrb[k]; fi = wri[k]; }
            ridx[lrow] = fi;
        }
        __syncthreads();
    }

    // ---- fused epilogue: wave w writes rows [wrow, wrow+16) ----
    #pragma unroll 4
    for (int j = 0; j < 16; ++j) {
        const int lrow = w * 16 + j;
        const int idx  = ridx[lrow];
        const int row  = row0 + lrow;
        const size_t xb = (size_t)row * DIM + lane * 4;
        float4 x = *(const float4*)(X + xb);
        float4 q = *(const float4*)(E + (size_t)idx * DIM + lane * 4);
        float4 dl = {q.x - x.x, q.y - x.y, q.z - x.z, q.w - x.w};
        float4 lo = {0.25f * dl.x * dl.x, 0.25f * dl.y * dl.y,
                     0.25f * dl.z * dl.z, 0.25f * dl.w * dl.w};
        float4 qs = {x.x + dl.x, x.y + dl.y, x.z + dl.z, x.w + dl.w};
        *(float4*)(loss + xb) = lo;
        *(float4*)(qst + xb)  = qs;
        const size_t ob = (size_t)row * CODES;
        const int slot = idx >> 2, r3 = idx & 3;
        #pragma unroll
        for (int jj = 0; jj < 4; ++jj) {
            f32x4 z = {0.f, 0.f, 0.f, 0.f};
            if (slot == jj * 64 + lane) z[r3] = 1.0f;
            __builtin_nontemporal_store(z, (f32x4*)(onehot + ob + jj * 256 + lane * 4));
        }
    }
}

extern "C" void kernel_launch(void* const* d_in, const int* in_sizes, int n_in,
                              void* d_out, int out_size, void* d_ws, size_t ws_size,
                              hipStream_t stream) {
    const float* X = (const float*)d_in[0];   // (65536, 256)
    const float* E = (const float*)d_in[1];   // (1024, 256)
    float* out = (float*)d_out;
    float* loss   = out;
    float* qst    = out + (size_t)BATCH * DIM;
    float* onehot = out + (size_t)2 * BATCH * DIM;

    char* ws = (char*)d_ws;
    float*          enorm  = (float*)ws;                        // 4 KB
    unsigned short* Eh     = (unsigned short*)(ws + 4096);      // 512 KB

    vq_prep<<<CODES, 64, 0, stream>>>(E, enorm, Eh);
    vq_fused<<<BATCH / 128, 512, 0, stream>>>(X, Eh, enorm, E,
                                              loss, qst, onehot);
}